// Round 4
// baseline (1010.182 us; speedup 1.0000x reference)
//
#include <hip/hip_runtime.h>
#include <hip/hip_bf16.h>
#include <cstdint>
#include <cstddef>

#define PIX   4096
#define PDYN  78016
#define LATD  512
#define CATD  2048

typedef unsigned short u16;
typedef __attribute__((ext_vector_type(8))) short bf16x8;
typedef __attribute__((ext_vector_type(4))) float f32x4;
#define MFMA16(a,b,c) __builtin_amdgcn_mfma_f32_16x16x32_bf16(a,b,c,0,0,0)

__device__ __forceinline__ float lrelu(float v) { return v > 0.f ? v : 0.2f * v; }
__device__ __forceinline__ unsigned bfbits(float x) {
  __hip_bfloat16 h = __float2bfloat16(x);
  return (unsigned)*(unsigned short*)&h;
}
__device__ __forceinline__ unsigned pack2(float a, float b) {
  return bfbits(a) | (bfbits(b) << 16);
}
union bfcast { unsigned u[4]; bf16x8 v; };

// ---------------- tiny utility kernels ----------------
__global__ void k_zero(float* __restrict__ p, int n) {
  int i = blockIdx.x * 256 + threadIdx.x;
  if (i < n) p[i] = 0.f;
}

__global__ void k_init_out(const float* __restrict__ x, const float* __restrict__ w_in,
                           const float* __restrict__ b_in, float* __restrict__ out) {
  int idx = blockIdx.x * 256 + threadIdx.x;
  int p = idx & 4095, o = (idx >> 12) & 63, b = idx >> 18;
  const float* xb = x + (size_t)b * 3 * PIX + p;
  out[idx] = b_in[o] + w_in[o*3+0]*xb[0] + w_in[o*3+1]*xb[PIX] + w_in[o*3+2]*xb[2*PIX];
}

__global__ void k_cat_init(const float* __restrict__ lat, float* __restrict__ cat) {
  int idx = blockIdx.x * 256 + threadIdx.x;     // 16*2048
  int j = idx & 2047, b = idx >> 11;
  cat[idx] = (j < 512) ? lat[b*512 + j] : 0.f;
}

// pe -> bf16 fragment-panel layout: peB[pt32][ft2][kc4][lane64][j8]
__global__ void k_pe(const float* __restrict__ pe, u16* __restrict__ peB) {
  int idx = blockIdx.x * 256 + threadIdx.x;     // 131072
  int j = idx & 7, lane = (idx >> 3) & 63, kc = (idx >> 9) & 3, ft = (idx >> 11) & 1, pt = idx >> 12;
  int f = ft*16 + (lane & 15);
  int p = pt*128 + kc*32 + (lane >> 4)*8 + j;
  peB[idx] = (f < 24) ? (u16)bfbits(pe[(size_t)f*PIX + p]) : (u16)0;
}

// inj_seq (64 x 512 f32) -> A-fragment bf16 panels [kb8][kc2][mt4][lane64][j8]
__global__ void k_afold(const float* __restrict__ inj_seq, u16* __restrict__ Abf) {
  int idx = blockIdx.x * 256 + threadIdx.x;     // 32768
  int j = idx & 7, lane = (idx >> 3) & 63, mt = (idx >> 9) & 3, kc = (idx >> 11) & 1, kb = idx >> 12;
  int m = mt*16 + (lane & 15);
  int k = kb*64 + kc*32 + (lane >> 4)*8 + j;
  Abf[idx] = (u16)bfbits(inj_seq[m*512 + k]);
}

// ---------------- perceive + instance-norm -> xn (bf16, normalized) ----------------
__device__ __forceinline__ void feat9(const float (*ch)[65], int h, int w, float* f) {
  f[0] = ch[h][w];
#pragma unroll
  for (int di = 0; di < 4; ++di) {
    int d = 1 << di;
    bool hm = (h - d) >= 0, hp = (h + d) < 64;
    bool wm = (w - d) >= 0, wp = (w + d) < 64;
    float tm = (hm && wm) ? ch[h-d][w-d] : 0.f;
    float t0 =  hm        ? ch[h-d][w  ] : 0.f;
    float tp = (hm && wp) ? ch[h-d][w+d] : 0.f;
    float mm =  wm        ? ch[h  ][w-d] : 0.f;
    float mp =  wp        ? ch[h  ][w+d] : 0.f;
    float bm = (hp && wm) ? ch[h+d][w-d] : 0.f;
    float b0 =  hp        ? ch[h+d][w  ] : 0.f;
    float bp = (hp && wp) ? ch[h+d][w+d] : 0.f;
    f[1 + 2*di] = (tp - tm + 2.f*(mp - mm) + bp - bm) * 0.125f;
    f[2 + 2*di] = (bm - tm + 2.f*(b0 - t0) + bp - tp) * 0.125f;
  }
}

__global__ __launch_bounds__(256) void k_prep(const float* __restrict__ out,
                                              __hip_bfloat16* __restrict__ xn) {
  __shared__ float ch[64][65];
  __shared__ float redS[4][9], redQ[4][9];
  __shared__ float mS[9], rS[9];
  int c = blockIdx.x, b = blockIdx.y, t = threadIdx.x;
  const float* src = out + ((size_t)b * 64 + c) * PIX;
  for (int j = 0; j < 16; ++j) { int idx = t + j*256; ch[idx >> 6][idx & 63] = src[idx]; }
  __syncthreads();
  float s[9], q[9];
#pragma unroll
  for (int k = 0; k < 9; ++k) { s[k] = 0.f; q[k] = 0.f; }
  for (int j = 0; j < 16; ++j) {
    int p = t + j*256; int h = p >> 6, w = p & 63;
    float f[9]; feat9(ch, h, w, f);
#pragma unroll
    for (int k = 0; k < 9; ++k) { s[k] += f[k]; q[k] += f[k]*f[k]; }
  }
#pragma unroll
  for (int off = 32; off; off >>= 1)
#pragma unroll
    for (int k = 0; k < 9; ++k) { s[k] += __shfl_down(s[k], off, 64); q[k] += __shfl_down(q[k], off, 64); }
  int lane = t & 63, wv = t >> 6;
  if (lane == 0)
#pragma unroll
    for (int k = 0; k < 9; ++k) { redS[wv][k] = s[k]; redQ[wv][k] = q[k]; }
  __syncthreads();
  if (t < 9) {
    float ss = 0.f, qq = 0.f;
    for (int w2 = 0; w2 < 4; ++w2) { ss += redS[w2][t]; qq += redQ[w2][t]; }
    float mean = ss * (1.f/4096.f);
    float var  = qq * (1.f/4096.f) - mean*mean;
    mS[t] = mean; rS[t] = rsqrtf(var + 1e-5f);
  }
  __syncthreads();
  for (int j = 0; j < 16; ++j) {
    int p = t + j*256; int h = p >> 6, w = p & 63;
    float f[9]; feat9(ch, h, w, f);
#pragma unroll
    for (int k = 0; k < 9; ++k)
      xn[((size_t)b * 576 + k*64 + c) * PIX + p] = __float2bfloat16((f[k] - mS[k]) * rS[k]);
  }
}

// ---------------- P-GEMM v2: barrier-free direct-fragment MFMA ----------------
// (64x512)@(512x78016). B fragments loaded straight from global in operand
// order (8 k-strided f32 per lane), cvt_pk in-register. No LDS, no syncthreads.
__global__ __launch_bounds__(256) void k_pgemm(
    const u16* __restrict__ Abf, const float* __restrict__ Bw,
    const float* __restrict__ bias, u16* __restrict__ Wst4,
    u16* __restrict__ KoutF4, float* __restrict__ biasf4) {
  int t = threadIdx.x;
  int lane = t & 63, wv = t >> 6;
  int col = lane & 15, quad = lane >> 4;
  int n0 = blockIdx.x * 128;

  f32x4 acc[4][2];
#pragma unroll
  for (int i = 0; i < 4; ++i) { acc[i][0] = {0.f,0.f,0.f,0.f}; acc[i][1] = {0.f,0.f,0.f,0.f}; }

  int nn[2]; bool vld[2]; size_t loff[2];
#pragma unroll
  for (int nt = 0; nt < 2; ++nt) {
    nn[nt] = n0 + wv*32 + nt*16 + col;
    vld[nt] = nn[nt] < PDYN;
    loff[nt] = (size_t)(quad*8)*PDYN + nn[nt];
  }

  for (int kb = 0; kb < 8; ++kb) {
    float bv[2][2][8];                       // [kc][nt][j]
#pragma unroll
    for (int kc = 0; kc < 2; ++kc) {
      const float* Brow = Bw + (size_t)(kb*64 + kc*32)*PDYN;
#pragma unroll
      for (int nt = 0; nt < 2; ++nt)
#pragma unroll
        for (int j = 0; j < 8; ++j)
          bv[kc][nt][j] = vld[nt] ? Brow[(size_t)j*PDYN + loff[nt]] : 0.f;
    }
#pragma unroll
    for (int kc = 0; kc < 2; ++kc) {
      bfcast bfr[2];
#pragma unroll
      for (int nt = 0; nt < 2; ++nt)
#pragma unroll
        for (int u = 0; u < 4; ++u)
          bfr[nt].u[u] = pack2(bv[kc][nt][2*u], bv[kc][nt][2*u+1]);
#pragma unroll
      for (int mt = 0; mt < 4; ++mt) {
        bf16x8 af = *(const bf16x8*)&Abf[(((kb*2 + kc)*4 + mt)*64 + lane) * 8];
        acc[mt][0] = MFMA16(af, bfr[0].v, acc[mt][0]);
        acc[mt][1] = MFMA16(af, bfr[1].v, acc[mt][1]);
      }
    }
  }

  // scatter epilogue: P[prow=cyc*16+b][pcol] -> folded layouts
#pragma unroll
  for (int nt = 0; nt < 2; ++nt) {
    int pcol = nn[nt];
    if (pcol >= PDYN) continue;
    float bb = bias[pcol];
#pragma unroll
    for (int mt = 0; mt < 4; ++mt) {
#pragma unroll
      for (int r = 0; r < 4; ++r) {
        int lb = mt*16 + quad*4 + r;           // latent row = cyc*16+b
        float v = acc[mt][nt][r] + bb;
        if (pcol < 36864) {                     // k_in[o][f]
          int o = pcol / 576, f = pcol - o*576;
          Wst4[(size_t)lb*73728 + (f>>5)*4096 + o*32 + (f&31)] = (u16)bfbits(v);
        } else if (pcol < 36928) {              // b_in
          biasf4[lb*192 + (pcol - 36864)] = v;
        } else if (pcol < 41024) {              // k_out[o][m]
          int q = pcol - 36928; int o = q >> 6, m = q & 63;
          int lk = ((m & 31) >> 3)*16 + (o & 15);
          KoutF4[(size_t)lb*4096 + (((o>>4)*2 + (m>>5))*64 + lk)*8 + (m & 7)] = (u16)bfbits(v);
        } else if (pcol < 41088) {              // b_out
          biasf4[lb*192 + 64 + (pcol - 41024)] = v;
        } else if (pcol < 77952) {              // k_sk[o][f]
          int q = pcol - 41088; int o = q / 576, f = q - o*576;
          Wst4[(size_t)lb*73728 + (f>>5)*4096 + (64 + o)*32 + (f&31)] = (u16)bfbits(v);
        } else {                                // b_sk
          biasf4[lb*192 + 128 + (pcol - 77952)] = v;
        }
      }
    }
  }
}

// ---------------- M=16 direct-fragment MFMA GEMM (otl w1) ----------------
// Cp[ks][16][N] partials = A(16xK f32) @ B(KxN f32), inline bf16 cvt, no LDS.
__global__ __launch_bounds__(256) void k_mgemm16(
    const float* __restrict__ A, const float* __restrict__ Bw,
    float* __restrict__ Cp, int N, int K) {
  int t = threadIdx.x;
  int lane = t & 63, wv = t >> 6;
  int col = lane & 15, quad = lane >> 4;
  int n0 = blockIdx.x * 128;
  int kchunk = K / gridDim.y;
  int kbeg = blockIdx.y * kchunk;

  f32x4 acc[2] = {{0.f,0.f,0.f,0.f},{0.f,0.f,0.f,0.f}};
  int n = n0 + wv*32 + col;
  size_t loff = (size_t)(quad*8)*N + n;
  const float* Arow = A + col*K + quad*8;

  for (int k0 = kbeg; k0 < kbeg + kchunk; k0 += 64) {
#pragma unroll
    for (int kc = 0; kc < 2; ++kc) {
      float4 a0 = *(const float4*)(Arow + k0 + kc*32);
      float4 a1 = *(const float4*)(Arow + k0 + kc*32 + 4);
      bfcast af;
      af.u[0] = pack2(a0.x, a0.y); af.u[1] = pack2(a0.z, a0.w);
      af.u[2] = pack2(a1.x, a1.y); af.u[3] = pack2(a1.z, a1.w);
      const float* Brow = Bw + (size_t)(k0 + kc*32)*N;
#pragma unroll
      for (int nt = 0; nt < 2; ++nt) {
        float bj[8];
#pragma unroll
        for (int j = 0; j < 8; ++j) bj[j] = Brow[(size_t)j*N + loff + nt*16];
        bfcast bfr;
#pragma unroll
        for (int u = 0; u < 4; ++u) bfr.u[u] = pack2(bj[2*u], bj[2*u+1]);
        acc[nt] = MFMA16(af.v, bfr.v, acc[nt]);
      }
    }
  }
  float* Cb = Cp + (size_t)blockIdx.y * 16 * N;
#pragma unroll
  for (int nt = 0; nt < 2; ++nt)
#pragma unroll
    for (int r = 0; r < 4; ++r)
      Cb[(size_t)(quad*4 + r)*N + n + nt*16] = acc[nt][r];
}

// ---------------- fused MFMA dyna_conv + k_out + freq ----------------
__global__ __launch_bounds__(256) void k_dyna(
    const u16* __restrict__ Wst4, const u16* __restrict__ xn,
    const u16* __restrict__ KoutF4, const u16* __restrict__ peB,
    const float* __restrict__ biasf4, float* __restrict__ out,
    float* __restrict__ cat, int cyc) {
  __shared__ u16 lds[16384];                 // 32 KB
  u16* As = lds;
  u16* Xl = lds + 8192;

  int t = threadIdx.x;
  int lane = t & 63, wv = t >> 6;
  int col = lane & 15, quad = lane >> 4;
  int b = blockIdx.y, p0 = blockIdx.x * 128;

  const u16* WB  = Wst4 + (size_t)(cyc*16 + b) * 73728;
  const u16* xnB = xn  + (size_t)b * 576 * PIX + p0;

  f32x4 acc[8][2];
#pragma unroll
  for (int i = 0; i < 8; ++i) { acc[i][0] = {0.f,0.f,0.f,0.f}; acc[i][1] = {0.f,0.f,0.f,0.f}; }

  int pg = t & 15, kq = t >> 4;

  for (int kb = 0; kb < 9; ++kb) {
    uint4 w[4];
    const uint4* wsrc = (const uint4*)(WB + (size_t)kb*8192 + t*32);
#pragma unroll
    for (int q = 0; q < 4; ++q) w[q] = wsrc[q];
    uint4 xr[4];
#pragma unroll
    for (int kk = 0; kk < 4; ++kk)
      xr[kk] = *(const uint4*)(xnB + (size_t)(kb*64 + kq*4 + kk)*PIX + pg*8);
    __syncthreads();
    {
      int m = t & 127, kg = t >> 7, m7 = m & 7;
#pragma unroll
      for (int q = 0; q < 4; ++q)
        *(uint4*)&As[m*64 + (((kg*4 + q) ^ m7) * 8)] = w[q];
    }
    const unsigned* xw = (const unsigned*)xr;
    unsigned pkl[8], pkh[8];
#pragma unroll
    for (int i = 0; i < 8; ++i) {
      unsigned sh = (i & 1) * 16;
      unsigned h0 = (xw[0  + (i>>1)] >> sh) & 0xffffu;
      unsigned h1 = (xw[4  + (i>>1)] >> sh) & 0xffffu;
      unsigned h2 = (xw[8  + (i>>1)] >> sh) & 0xffffu;
      unsigned h3 = (xw[12 + (i>>1)] >> sh) & 0xffffu;
      pkl[i] = h0 | (h1 << 16);
      pkh[i] = h2 | (h3 << 16);
    }
    int ch0 = kq >> 1, sub = (kq & 1) * 4;
#pragma unroll
    for (int jj = 0; jj < 8; ++jj) {
      int i = (jj + pg) & 7;
      int p = pg*8 + i;
      *(uint2*)&Xl[p*64 + ((ch0 ^ i) * 8) + sub] = make_uint2(pkl[i], pkh[i]);
    }
    __syncthreads();
#pragma unroll
    for (int kc = 0; kc < 2; ++kc) {
      bf16x8 bfr[2];
#pragma unroll
      for (int nt = 0; nt < 2; ++nt) {
        int n = wv*32 + nt*16 + col;
        bfr[nt] = *(const bf16x8*)&Xl[n*64 + (((kc*4 + quad) ^ (n & 7)) * 8)];
      }
#pragma unroll
      for (int mt = 0; mt < 8; ++mt) {
        int m = mt*16 + col;
        bf16x8 af = *(const bf16x8*)&As[m*64 + (((kc*4 + quad) ^ (m & 7)) * 8)];
        acc[mt][0] = MFMA16(af, bfr[0], acc[mt][0]);
        acc[mt][1] = MFMA16(af, bfr[1], acc[mt][1]);
      }
    }
  }
  __syncthreads();

  // E1: h = lrelu(acc_in + b_in) -> B-fragment layout in As
  const float* bfB = biasf4 + (size_t)(cyc*16 + b) * 192;
#pragma unroll
  for (int mt = 0; mt < 4; ++mt) {
    float bm[4];
#pragma unroll
    for (int r = 0; r < 4; ++r) bm[r] = bfB[mt*16 + quad*4 + r];
#pragma unroll
    for (int nt = 0; nt < 2; ++nt) {
      unsigned lo = pack2(lrelu(acc[mt][nt][0] + bm[0]), lrelu(acc[mt][nt][1] + bm[1]));
      unsigned hi = pack2(lrelu(acc[mt][nt][2] + bm[2]), lrelu(acc[mt][nt][3] + bm[3]));
      int nl = nt*16 + col;
      int ch = (mt*2 + (quad >> 1)) ^ (nl & 7);
      *(uint2*)&As[(wv*32 + nl)*64 + ch*8 + (quad & 1)*4] = make_uint2(lo, hi);
    }
  }
  __syncthreads();

  // E2: y = k_out @ h; res = acc_sk + y + (b_sk + b_out)
  f32x4 yac[4][2];
#pragma unroll
  for (int i = 0; i < 4; ++i) { yac[i][0] = {0.f,0.f,0.f,0.f}; yac[i][1] = {0.f,0.f,0.f,0.f}; }
  const u16* kofB = KoutF4 + (size_t)(cyc*16 + b) * 4096;
#pragma unroll
  for (int kc = 0; kc < 2; ++kc) {
    bf16x8 hb[2];
#pragma unroll
    for (int nt = 0; nt < 2; ++nt) {
      int nl = nt*16 + col;
      hb[nt] = *(const bf16x8*)&As[(wv*32 + nl)*64 + (((kc*4 + quad) ^ (nl & 7)) * 8)];
    }
#pragma unroll
    for (int ot = 0; ot < 4; ++ot) {
      bf16x8 ka = *(const bf16x8*)&kofB[((ot*2 + kc)*64 + lane) * 8];
      yac[ot][0] = MFMA16(ka, hb[0], yac[ot][0]);
      yac[ot][1] = MFMA16(ka, hb[1], yac[ot][1]);
    }
  }
#pragma unroll
  for (int ot = 0; ot < 4; ++ot) {
    float bo[4];
#pragma unroll
    for (int r = 0; r < 4; ++r) {
      int o = ot*16 + quad*4 + r;
      bo[r] = bfB[64 + o] + bfB[128 + o];
    }
#pragma unroll
    for (int nt = 0; nt < 2; ++nt) {
      int pl = wv*32 + nt*16 + col;
#pragma unroll
      for (int r = 0; r < 4; ++r) {
        float rs = acc[4 + ot][nt][r] + yac[ot][nt][r] + bo[r];
        int o = ot*16 + quad*4 + r;
        out[((size_t)b*64 + o)*PIX + p0 + pl] = rs;
        Xl[o*128 + (((pl >> 3) ^ (o & 7)) * 8) + (pl & 7)] = (u16)bfbits(rs);
      }
    }
  }
  __syncthreads();

  // freq via MFMA
  f32x4 fac[4][2];
#pragma unroll
  for (int i = 0; i < 4; ++i) { fac[i][0] = {0.f,0.f,0.f,0.f}; fac[i][1] = {0.f,0.f,0.f,0.f}; }
  bf16x8 pb[2];
#pragma unroll
  for (int ft = 0; ft < 2; ++ft)
    pb[ft] = *(const bf16x8*)&peB[((((size_t)blockIdx.x*2 + ft)*4 + wv)*64 + lane) * 8];
#pragma unroll
  for (int mt = 0; mt < 4; ++mt) {
    int o = mt*16 + col;
    bf16x8 ar = *(const bf16x8*)&Xl[o*128 + (((wv*4 + quad) ^ (o & 7)) * 8)];
    fac[mt][0] = MFMA16(ar, pb[0], fac[mt][0]);
    fac[mt][1] = MFMA16(ar, pb[1], fac[mt][1]);
  }
  __syncthreads();
  float* fred = (float*)lds;
#pragma unroll
  for (int mt = 0; mt < 4; ++mt)
#pragma unroll
    for (int ft = 0; ft < 2; ++ft)
#pragma unroll
      for (int r = 0; r < 4; ++r)
        fred[(wv*64 + mt*16 + quad*4 + r)*32 + ft*16 + col] = fac[mt][ft][r];
  __syncthreads();
  for (int pr = t; pr < 1536; pr += 256) {
    int o = pr / 24, f = pr - o*24;
    float s = fred[o*32 + f] + fred[(64 + o)*32 + f] + fred[(128 + o)*32 + f] + fred[(192 + o)*32 + f];
    atomicAdd(&cat[b*CATD + 512 + o*24 + f], s * (1.f/4096.f));
  }
}

// ---------------- skinny f32 GEMMs (latent path), partial-only + dual-B ----------------
__global__ __launch_bounds__(256) void gemm_skinny(
    const float* __restrict__ A, const float* __restrict__ Bm,
    float* __restrict__ C, int N, int K) {
  __shared__ float As[16][17];
  __shared__ float Bs[16][64];
  int t = threadIdx.x;
  int row = t & 15, cg = t >> 4;
  int n0 = blockIdx.x * 64;
  int ks = gridDim.y;
  int kchunk = K / ks;
  int k0base = blockIdx.y * kchunk;
  float acc[4] = {0.f, 0.f, 0.f, 0.f};
  for (int k0 = k0base; k0 < k0base + kchunk; k0 += 16) {
    { int lr = t >> 4, lc = t & 15; As[lc][lr] = A[(size_t)lr*K + k0 + lc]; }
#pragma unroll
    for (int j = 0; j < 4; ++j) {
      int idx = t + j*256;
      int kr = idx >> 6, nc = idx & 63;
      Bs[kr][nc] = Bm[(size_t)(k0 + kr)*N + n0 + nc];
    }
    __syncthreads();
#pragma unroll
    for (int kk = 0; kk < 16; ++kk) {
      float a = As[kk][row];
      float4 bv = *(const float4*)&Bs[kk][cg*4];
      acc[0] += a*bv.x; acc[1] += a*bv.y; acc[2] += a*bv.z; acc[3] += a*bv.w;
    }
    __syncthreads();
  }
  float* Pp = C + (size_t)blockIdx.y * 16 * N;
#pragma unroll
  for (int j = 0; j < 4; ++j) Pp[(size_t)row*N + n0 + cg*4 + j] = acc[j];
}

__global__ __launch_bounds__(256) void gemm_skinny2(
    const float* __restrict__ A,
    const float* __restrict__ B1, float* __restrict__ C1, int N1, int tiles1,
    const float* __restrict__ B2, float* __restrict__ C2, int N2, int K) {
  __shared__ float As[16][17];
  __shared__ float Bs[16][64];
  int bx = blockIdx.x;
  const float* Bm; float* C; int N, n0;
  if (bx < tiles1) { Bm = B1; C = C1; N = N1; n0 = bx*64; }
  else             { Bm = B2; C = C2; N = N2; n0 = (bx - tiles1)*64; }
  int t = threadIdx.x;
  int row = t & 15, cg = t >> 4;
  int ks = gridDim.y;
  int kchunk = K / ks;
  int k0base = blockIdx.y * kchunk;
  float acc[4] = {0.f, 0.f, 0.f, 0.f};
  for (int k0 = k0base; k0 < k0base + kchunk; k0 += 16) {
    { int lr = t >> 4, lc = t & 15; As[lc][lr] = A[(size_t)lr*K + k0 + lc]; }
#pragma unroll
    for (int j = 0; j < 4; ++j) {
      int idx = t + j*256;
      int kr = idx >> 6, nc = idx & 63;
      Bs[kr][nc] = Bm[(size_t)(k0 + kr)*N + n0 + nc];
    }
    __syncthreads();
#pragma unroll
    for (int kk = 0; kk < 16; ++kk) {
      float a = As[kk][row];
      float4 bv = *(const float4*)&Bs[kk][cg*4];
      acc[0] += a*bv.x; acc[1] += a*bv.y; acc[2] += a*bv.z; acc[3] += a*bv.w;
    }
    __syncthreads();
  }
  float* Pp = C + (size_t)blockIdx.y * 16 * N;
#pragma unroll
  for (int j = 0; j < 4; ++j) Pp[(size_t)row*N + n0 + cg*4 + j] = acc[j];
}

// C[idx] (=|+=) act( bias1[col] + sum P1 (+ bias2[col] + sum P2) )
__global__ void k_reduce(float* __restrict__ C,
                         const float* __restrict__ P1, int ns1, const float* __restrict__ bias1,
                         const float* __restrict__ P2, int ns2, const float* __restrict__ bias2,
                         int nmask, int total, int act, int accum) {
  int idx = blockIdx.x * 256 + threadIdx.x;
  if (idx >= total) return;
  int col = idx & nmask;
  float v = bias1[col];
  for (int s = 0; s < ns1; ++s) v += P1[(size_t)s*total + idx];
  if (P2) { v += bias2[col]; for (int s = 0; s < ns2; ++s) v += P2[(size_t)s*total + idx]; }
  if (act) v = lrelu(v);
  if (accum) v += C[idx];
  C[idx] = v;
}

// ---------------- host ----------------
extern "C" void kernel_launch(void* const* d_in, const int* in_sizes, int n_in,
                              void* d_out, int out_size, void* d_ws, size_t ws_size,
                              hipStream_t stream) {
  const float* x      = (const float*)d_in[0];
  const float* inj0   = (const float*)d_in[1];
  const float* w_in   = (const float*)d_in[2];
  const float* b_in   = (const float*)d_in[3];
  const float* fl_w1  = (const float*)d_in[4];
  const float* fl_b1  = (const float*)d_in[5];
  const float* fl_w2  = (const float*)d_in[6];
  const float* fl_b2  = (const float*)d_in[7];
  const float* fl_ws  = (const float*)d_in[8];
  const float* fl_bs  = (const float*)d_in[9];
  const float* dyn_w  = (const float*)d_in[10];
  const float* dyn_b  = (const float*)d_in[11];
  const float* pe     = (const float*)d_in[12];
  const float* otl_w1 = (const float*)d_in[13];
  const float* otl_b1 = (const float*)d_in[14];
  const float* otl_w2 = (const float*)d_in[15];
  const float* otl_b2 = (const float*)d_in[16];
  const float* otl_ws = (const float*)d_in[17];
  const float* otl_bs = (const float*)d_in[18];
  const float* ltl_w  = (const float*)d_in[19];
  const float* ltl_b  = (const float*)d_in[20];
  float* outF = (float*)d_out;

  char* w = (char*)d_ws;
  float* inj_seq = (float*)(w + 0);            // 131072
  float* tmpA    = (float*)(w + 131072);       // 131072
  float* lat     = (float*)(w + 262144);       // 32768
  float* cat     = (float*)(w + 294912);       // 131072
  float* biasf4  = (float*)(w + 425984);       // 64*192*4 = 49152
  float* part1   = (float*)(w + 475136);       // up to 2 MB
  float* part2   = (float*)(w + 2572288);      // 524288
  float* part3   = (float*)(w + 3096576);      // 524288
  u16*   Wst4    = (u16*)  (w + 3620864);      // 9437184
  u16*   KoutF4  = (u16*)  (w + 13058048);     // 524288
  u16*   Abf     = (u16*)  (w + 13582336);     // 65536
  u16*   peB     = (u16*)  (w + 13647872);     // 262144
  float* outb    = (float*)(w + 13910016);     // 16777216
  u16*   xnb     = (u16*)  (w + 30687232);     // 75497472

  k_zero<<<32, 256, 0, stream>>>(lat, 16*512);
  k_init_out<<<16384, 256, 0, stream>>>(x, w_in, b_in, outb);
  k_pe<<<512, 256, 0, stream>>>(pe, peB);

  // latent chain (all 4 cycles upfront): 4 launches/cycle
  for (int c = 0; c < 4; ++c) {
    const float* src = (c == 0) ? inj0 : (inj_seq + (size_t)(c-1)*16*LATD);
    float* dst = inj_seq + (size_t)c*16*LATD;
    gemm_skinny2<<<dim3(16,8), 256, 0, stream>>>(src, fl_w1, part2, 512, 8, fl_ws, part3, 512, 512);
    k_reduce<<<32, 256, 0, stream>>>(tmpA, part2, 8, fl_b1, nullptr, 0, nullptr, 511, 8192, 1, 0);
    gemm_skinny<<<dim3(8,8), 256, 0, stream>>>(tmpA, fl_w2, part2, 512, 512);
    k_reduce<<<32, 256, 0, stream>>>(dst, part3, 8, fl_bs, part2, 8, fl_b2, 511, 8192, 0, 0);
  }
  k_afold<<<128, 256, 0, stream>>>(inj_seq, Abf);
  k_pgemm<<<610, 256, 0, stream>>>(Abf, dyn_w, dyn_b, Wst4, KoutF4, biasf4);

  for (int c = 0; c < 4; ++c) {
    k_prep<<<dim3(64,16), 256, 0, stream>>>(outb, (__hip_bfloat16*)xnb);
    k_cat_init<<<128, 256, 0, stream>>>(lat, cat);
    k_dyna<<<dim3(32,16), 256, 0, stream>>>(Wst4, xnb, KoutF4, peB, biasf4, outb, cat, c);
    // otl lin_res: w1 via MFMA direct-fragment (ks=8), ws/w2 f32 skinny
    k_mgemm16<<<dim3(16,8), 256, 0, stream>>>(cat, otl_w1 + (size_t)c*CATD*CATD, part1, 2048, 2048);
    gemm_skinny<<<dim3(8,16), 256, 0, stream>>>(cat, otl_ws + (size_t)c*CATD*LATD, part3, 512, 2048);
    k_reduce<<<128, 256, 0, stream>>>(tmpA, part1, 8, otl_b1 + c*CATD,
                                      nullptr, 0, nullptr, 2047, 16*2048, 1, 0);
    gemm_skinny<<<dim3(8,16), 256, 0, stream>>>(tmpA, otl_w2 + (size_t)c*CATD*LATD, part2, 512, 2048);
    k_reduce<<<32, 256, 0, stream>>>(lat, part3, 16, otl_bs + c*LATD,
                                     part2, 16, otl_b2 + c*LATD, 511, 16*512, 0, 0);
  }
  gemm_skinny<<<dim3(8,8), 256, 0, stream>>>(lat, ltl_w, part2, 512, 512);
  k_reduce<<<32, 256, 0, stream>>>(outF, part2, 8, ltl_b, nullptr, 0, nullptr, 511, 8192, 0, 0);
}